// Round 1
// baseline (436.691 us; speedup 1.0000x reference)
//
#include <hip/hip_runtime.h>

// out[i] = (2*i_local+1)*state[i] + param[i] - w*grad[i], per segment.
// Segments (in float4 units): [0,2048) seg0, [2048,4096) seg1, [4096,5120) seg2.
__global__ __launch_bounds__(256) void hippo_fused_kernel(
    const float4* __restrict__ p0, const float4* __restrict__ g0, const float4* __restrict__ s0,
    const float4* __restrict__ p1, const float4* __restrict__ g1, const float4* __restrict__ s1,
    const float4* __restrict__ p2, const float4* __restrict__ g2, const float4* __restrict__ s2,
    const float* __restrict__ w,
    float4* __restrict__ out)
{
    int v = blockIdx.x * blockDim.x + threadIdx.x;  // 0..5119 (float4 index)
    if (v >= 5120) return;

    float wv = *w;

    const float4* p;
    const float4* g;
    const float4* s;
    int local;  // float4 index within the segment
    if (v < 2048)      { p = p0; g = g0; s = s0; local = v;        }
    else if (v < 4096) { p = p1; g = g1; s = s1; local = v - 2048; }
    else               { p = p2; g = g2; s = s2; local = v - 4096; }

    float4 pv = p[local];
    float4 gv = g[local];
    float4 sv = s[local];

    // element index base within segment
    float d0 = 2.0f * (float)(4 * local) + 1.0f;  // exact for these sizes

    float4 o;
    o.x = __fsub_rn(__fadd_rn(__fmul_rn(d0,        sv.x), pv.x), __fmul_rn(wv, gv.x));
    o.y = __fsub_rn(__fadd_rn(__fmul_rn(d0 + 2.0f, sv.y), pv.y), __fmul_rn(wv, gv.y));
    o.z = __fsub_rn(__fadd_rn(__fmul_rn(d0 + 4.0f, sv.z), pv.z), __fmul_rn(wv, gv.z));
    o.w = __fsub_rn(__fadd_rn(__fmul_rn(d0 + 6.0f, sv.w), pv.w), __fmul_rn(wv, gv.w));

    out[v] = o;
}

extern "C" void kernel_launch(void* const* d_in, const int* in_sizes, int n_in,
                              void* d_out, int out_size, void* d_ws, size_t ws_size,
                              hipStream_t stream)
{
    // setup_inputs order: param0,grad0,state0,A0, param1,grad1,state1,A1,
    //                     param2,grad2,state2,A2, weights
    const float4* p0 = (const float4*)d_in[0];
    const float4* g0 = (const float4*)d_in[1];
    const float4* s0 = (const float4*)d_in[2];
    const float4* p1 = (const float4*)d_in[4];
    const float4* g1 = (const float4*)d_in[5];
    const float4* s1 = (const float4*)d_in[6];
    const float4* p2 = (const float4*)d_in[8];
    const float4* g2 = (const float4*)d_in[9];
    const float4* s2 = (const float4*)d_in[10];
    const float*  w  = (const float*)d_in[12];

    float4* out = (float4*)d_out;  // 20480 floats = 5120 float4, segments concatenated

    const int total_v4 = 5120;
    const int block = 256;
    const int grid = (total_v4 + block - 1) / block;  // 20
    hippo_fused_kernel<<<grid, block, 0, stream>>>(p0, g0, s0, p1, g1, s1, p2, g2, s2, w, out);
}